// Round 8
// baseline (1167.936 us; speedup 1.0000x reference)
//
#include <hip/hip_runtime.h>
#include <hip/hip_bf16.h>
#include <math.h>

#define TTOK 8192
#define DM   1024
#define NE   8
#define FH   4096
#define ECAP 8192

typedef __attribute__((ext_vector_type(8))) short bf16x8;
typedef __attribute__((ext_vector_type(4))) float f32x4;

__device__ __forceinline__ unsigned short f2bf(float f) {
  union { float f; unsigned u; } v; v.f = f;
  unsigned r = v.u + 0x7fffu + ((v.u >> 16) & 1u);
  return (unsigned short)(r >> 16);
}

// async global->LDS, 16B per lane; LDS dst must be wave-uniform-base + lane*16
__device__ __forceinline__ void async16(const unsigned short* g, unsigned short* l) {
  __builtin_amdgcn_global_load_lds(
      (const __attribute__((address_space(1))) void*)g,
      (__attribute__((address_space(3))) void*)l, 16, 0, 0);
}

// exact-gelu via Abramowitz-Stegun 7.1.26 erf approx (|err| <= 1.5e-7)
__device__ __forceinline__ float gelu_erf(float v) {
  float x = v * 0.70710678118654752f;
  float ax = fabsf(x);
  float t = __frcp_rn(1.0f + 0.3275911f * ax);
  float poly = t * (0.254829592f + t * (-0.284496736f +
               t * (1.421413741f + t * (-1.453152027f + t * 1.061405429f))));
  float erfa = 1.0f - poly * __expf(-ax * ax);
  float erfx = copysignf(erfa, x);
  return 0.5f * v * (1.0f + erfx);
}

// ---------------- x -> bf16 ----------------
__global__ void cvt_x(const float* __restrict__ x, unsigned short* __restrict__ xb, int n4) {
  int id = blockIdx.x * 256 + threadIdx.x;
  if (id >= n4) return;
  float4 v = ((const float4*)x)[id];
  ushort4 o;
  o.x = f2bf(v.x); o.y = f2bf(v.y); o.z = f2bf(v.z); o.w = f2bf(v.w);
  ((ushort4*)xb)[id] = o;
}

// ---------------- fp32 [NE][R][Cc] -> bf16 [NE][Cc][R] (transpose+convert) ----
__global__ __launch_bounds__(256) void transpose_cvt(
    const float* __restrict__ src, unsigned short* __restrict__ dst, int R, int Cc) {
  __shared__ unsigned short t[64 * 72];
  int e = blockIdx.z;
  int c0 = blockIdx.x * 64, r0 = blockIdx.y * 64;
  int tid = threadIdx.x;
  const float* sp = src + (size_t)e * R * Cc;
  unsigned short* dp = dst + (size_t)e * R * Cc;
#pragma unroll
  for (int p = 0; p < 4; ++p) {
    int idx = p * 256 + tid;
    int row = idx >> 4;
    int c4 = (idx & 15) * 4;
    float4 v = *(const float4*)(sp + (size_t)(r0 + row) * Cc + c0 + c4);
    t[(c4 + 0) * 72 + row] = f2bf(v.x);
    t[(c4 + 1) * 72 + row] = f2bf(v.y);
    t[(c4 + 2) * 72 + row] = f2bf(v.z);
    t[(c4 + 3) * 72 + row] = f2bf(v.w);
  }
  __syncthreads();
#pragma unroll
  for (int p = 0; p < 4; ++p) {
    int idx = p * 256 + tid;
    int crow = idx >> 4;
    int r4 = (idx & 15) * 4;
    ushort4 o = *(ushort4*)(&t[crow * 72 + r4]);
    *(ushort4*)(dp + (size_t)(c0 + crow) * R + r0 + r4) = o;
  }
}

// ---------------- gating: softmax + top2 + bucket append ----------------
__global__ __launch_bounds__(256) void gate_kernel(
    const float* __restrict__ x, const float* __restrict__ wg,
    int* __restrict__ cnt, int* __restrict__ ent_tok, float* __restrict__ ent_w) {
  __shared__ float wls[NE * DM];
  int tid = threadIdx.x;
  for (int i = tid; i < NE * DM / 4; i += 256)
    ((float4*)wls)[i] = ((const float4*)wg)[i];
  __syncthreads();

  int wave = tid >> 6, lane = tid & 63;
  int t = blockIdx.x * 4 + wave;
  const float* xp = x + (size_t)t * DM;
  float acc[NE];
#pragma unroll
  for (int e = 0; e < NE; ++e) acc[e] = 0.f;
#pragma unroll
  for (int i = 0; i < 16; ++i) {
    float xv = xp[i * 64 + lane];
#pragma unroll
    for (int e = 0; e < NE; ++e) acc[e] += xv * wls[e * DM + i * 64 + lane];
  }
#pragma unroll
  for (int e = 0; e < NE; ++e) {
    float v = acc[e];
    for (int off = 32; off; off >>= 1) v += __shfl_xor(v, off, 64);
    acc[e] = v;
  }
  if (lane == 0) {
    float mx = acc[0];
#pragma unroll
    for (int e = 1; e < NE; ++e) mx = fmaxf(mx, acc[e]);
    float p[NE], s = 0.f;
#pragma unroll
    for (int e = 0; e < NE; ++e) { p[e] = __expf(acc[e] - mx); s += p[e]; }
    float inv = 1.f / s;
#pragma unroll
    for (int e = 0; e < NE; ++e) p[e] *= inv;
    int i0 = 0; float m0v = p[0];
#pragma unroll
    for (int e = 1; e < NE; ++e) if (p[e] > m0v) { m0v = p[e]; i0 = e; }
    int i1 = -1; float m1v = -1.f;
#pragma unroll
    for (int e = 0; e < NE; ++e) if (e != i0 && p[e] > m1v) { m1v = p[e]; i1 = e; }
    int pos0 = atomicAdd(&cnt[i0], 1);
    ent_tok[i0 * ECAP + pos0] = t * 2;
    ent_w[i0 * ECAP + pos0] = m0v;
    int pos1 = atomicAdd(&cnt[i1], 1);
    ent_tok[i1 * ECAP + pos1] = t * 2 + 1;
    ent_w[i1 * ECAP + pos1] = m1v;
  }
}

// ---------------- exclusive scan of expert counts ----------------
__global__ void scan_cnt(const int* __restrict__ cnt, int* __restrict__ base) {
  if (threadIdx.x == 0) {
    int s = 0;
    for (int e = 0; e < NE; ++e) { base[e] = s; s += cnt[e]; }
  }
}

// =====================================================================
// 2-phase 256x256 grouped GEMM (R0's verified 2-phase template, tile
// parameter 128->256; m230/m248 measured 655-682 TF for this quadrant).
//   512 threads = 8 waves (2M x 4N), per-wave 128x64 out, acc[8][4]
//   BK=32 double-buffered, LDS 64 KiB, 4 async16/thread per K-step.
//   Sync structure identical to R0: __syncthreads() per half-step,
//   compiler inserts all waitcnts. No swizzle (T2 null at 2ph).
// =====================================================================

#define STG(b, k0) {                                              \
    async16(pA0 + (k0), &sA[b][tid * 8]);                         \
    async16(pA1 + (k0), &sA[b][4096 + tid * 8]);                  \
    async16(pB0 + (k0), &sB[b][tid * 8]);                         \
    async16(pB1 + (k0), &sB[b][4096 + tid * 8]);                  \
  }

#define CMP(b)                                                                 \
  {                                                                            \
    bf16x8 af[8], bfr[4];                                                      \
    _Pragma("unroll") for (int im = 0; im < 8; ++im)                           \
      af[im] = *(const bf16x8*)(&sA[b][(wm * 128 + im * 16 + l16) * 32 + q * 8]); \
    _Pragma("unroll") for (int in = 0; in < 4; ++in)                           \
      bfr[in] = *(const bf16x8*)(&sB[b][(wn * 64 + in * 16 + l16) * 32 + q * 8]); \
    _Pragma("unroll") for (int im = 0; im < 8; ++im)                           \
      _Pragma("unroll") for (int in = 0; in < 4; ++in)                         \
        acc[im][in] = __builtin_amdgcn_mfma_f32_16x16x32_bf16(af[im], bfr[in], acc[im][in], 0, 0, 0); \
  }

// GELU=true : A = gather(xb via ent_tok), out = gelu(acc+bias) -> bf16 hout
// GELU=false: A = hbuf rows (be+i),       out = w*(acc+bias)   -> f32 yout
template <int KTOT, int NTOT, bool GELU>
__global__ __launch_bounds__(512, 2) void moe_gemm2p(
    const unsigned short* __restrict__ Asrc, const unsigned short* __restrict__ Bsrc,
    const float* __restrict__ bias, const int* __restrict__ cnt,
    const int* __restrict__ base, const int* __restrict__ ent_tok,
    const float* __restrict__ ent_w, unsigned short* __restrict__ hout,
    float* __restrict__ yout) {
  const int bid = blockIdx.x;
  const int e = bid & 7;              // XCD pin
  const int j = bid >> 3;
  const int mt = j & 31;              // m inner -> neighbors share B panel
  const int nt = j >> 5;
  const int C = cnt[e];
  const int m0 = mt * 256;
  if (m0 >= C) return;
  const int n0 = nt * 256;
  const int be = base[e];
  const int tid = threadIdx.x;
  const int lane = tid & 63, wave = tid >> 6;
  const int wm = wave >> 2;           // 0..1  (M half)
  const int wn = wave & 3;            // 0..3  (N quarter)
  const int q = lane >> 4, l16 = lane & 15;

  __shared__ unsigned short sA[2][256 * 32];   // [buf][row][32] row-major
  __shared__ unsigned short sB[2][256 * 32];

  const int r = tid >> 2;             // 0..127
  const int kq = (tid & 3) * 8;       // k-offset 0/8/16/24
  int i0 = m0 + r;       if (i0 >= C) i0 = C - 1;
  int i1 = m0 + 128 + r; if (i1 >= C) i1 = C - 1;
  size_t a0, a1;
  if (GELU) { a0 = (size_t)(ent_tok[e * ECAP + i0] >> 1); a1 = (size_t)(ent_tok[e * ECAP + i1] >> 1); }
  else      { a0 = (size_t)(be + i0);                     a1 = (size_t)(be + i1); }
  const unsigned short* pA0 = Asrc + a0 * (size_t)KTOT + kq;
  const unsigned short* pA1 = Asrc + a1 * (size_t)KTOT + kq;
  const unsigned short* pB0 = Bsrc + ((size_t)e * NTOT + n0 + r) * (size_t)KTOT + kq;
  const unsigned short* pB1 = pB0 + (size_t)128 * KTOT;

  f32x4 acc[8][4];
#pragma unroll
  for (int i = 0; i < 8; ++i)
#pragma unroll
    for (int jj = 0; jj < 4; ++jj) acc[i][jj] = (f32x4){0.f, 0.f, 0.f, 0.f};

  // prologue: k=0 into buf 0
  STG(0, 0)

#pragma unroll 1
  for (int k0 = 0; k0 < KTOT; k0 += 64) {
    __syncthreads();               // drains buf0(k0) loads
    if (k0 + 32 < KTOT) STG(1, k0 + 32)
    CMP(0)
    __syncthreads();               // drains buf1(k0+32) loads
    if (k0 + 64 < KTOT) STG(0, k0 + 64)
    CMP(1)
  }

  // ---- epilogue ----
  float bl[4];
#pragma unroll
  for (int in2 = 0; in2 < 4; ++in2)
    bl[in2] = bias[(size_t)e * NTOT + n0 + wn * 64 + in2 * 16 + l16];

#pragma unroll
  for (int im = 0; im < 8; ++im)
#pragma unroll
    for (int rr = 0; rr < 4; ++rr) {
      const int gm = m0 + wm * 128 + im * 16 + q * 4 + rr;
      if (gm >= C) continue;
      if (GELU) {
        const size_t bas = (size_t)(be + gm) * NTOT + n0;
#pragma unroll
        for (int in2 = 0; in2 < 4; ++in2) {
          const int n = wn * 64 + in2 * 16 + l16;
          hout[bas + n] = f2bf(gelu_erf(acc[im][in2][rr] + bl[in2]));
        }
      } else {
        const int rowid = ent_tok[e * ECAP + gm];
        const float w = ent_w[e * ECAP + gm];
        const size_t bas = (size_t)rowid * NTOT + n0;
#pragma unroll
        for (int in2 = 0; in2 < 4; ++in2) {
          const int n = wn * 64 + in2 * 16 + l16;
          yout[bas + n] = w * (acc[im][in2][rr] + bl[in2]);
        }
      }
    }
}

// ---------------- combine: out[t] = y[2t] + y[2t+1] ----------------
__global__ void combine_k(const float* __restrict__ y, float* __restrict__ out, int n4) {
  int id = blockIdx.x * 256 + threadIdx.x;
  if (id >= n4) return;
  int t = id >> 8;   // 256 float4 per 1024-elem row
  int c = id & 255;
  float4 a = ((const float4*)y)[((size_t)t * 2) * 256 + c];
  float4 b = ((const float4*)y)[((size_t)t * 2 + 1) * 256 + c];
  float4 o = {a.x + b.x, a.y + b.y, a.z + b.z, a.w + b.w};
  ((float4*)out)[id] = o;
}

extern "C" void kernel_launch(void* const* d_in, const int* in_sizes, int n_in,
                              void* d_out, int out_size, void* d_ws, size_t ws_size,
                              hipStream_t stream) {
  const float* x  = (const float*)d_in[0];
  const float* wg = (const float*)d_in[1];
  const float* W1 = (const float*)d_in[2];
  const float* b1 = (const float*)d_in[3];
  const float* W2 = (const float*)d_in[4];
  const float* b2 = (const float*)d_in[5];
  float* out = (float*)d_out;

  char* ws = (char*)d_ws;
  size_t off = 0;
  unsigned short* xb = (unsigned short*)(ws + off); off += (size_t)TTOK * DM * 2;        // 16 MB
  int* cnt = (int*)(ws + off); off += 128;
  int* base = (int*)(ws + off); off += 128;
  int* ent_tok = (int*)(ws + off); off += (size_t)NE * ECAP * 4;                         // 256 KB
  float* ent_w = (float*)(ws + off); off += (size_t)NE * ECAP * 4;                       // 256 KB
  unsigned short* W1T = (unsigned short*)(ws + off); off += (size_t)NE * DM * FH * 2;    // 64 MB
  unsigned short* W2T = (unsigned short*)(ws + off); off += (size_t)NE * FH * DM * 2;    // 64 MB
  unsigned short* hbuf = (unsigned short*)(ws + off); off += (size_t)TTOK * 2 * FH * 2;  // 128 MB
  // ybuf overlays W1T: W1T is dead after gemm1, regenerated next launch before gemm1
  float* ybuf = (float*)W1T;                                                             // 64 MB

  hipMemsetAsync(cnt, 0, 128, stream);
  cvt_x<<<TTOK * DM / 4 / 256, 256, 0, stream>>>(x, xb, TTOK * DM / 4);
  gate_kernel<<<TTOK / 4, 256, 0, stream>>>(x, wg, cnt, ent_tok, ent_w);
  scan_cnt<<<1, 64, 0, stream>>>(cnt, base);
  dim3 t1(FH / 64, DM / 64, NE);
  transpose_cvt<<<t1, 256, 0, stream>>>(W1, W1T, DM, FH);
  dim3 t2(DM / 64, FH / 64, NE);
  transpose_cvt<<<t2, 256, 0, stream>>>(W2, W2T, FH, DM);
  // GEMM1: 8 experts x 32 m-tiles x 16 n-tiles = 4096 blocks (early-exit on m0>=C)
  moe_gemm2p<DM, FH, true><<<NE * 32 * (FH / 256), 512, 0, stream>>>(
      xb, W1T, b1, cnt, base, ent_tok, ent_w, hbuf, nullptr);
  // GEMM2: 8 experts x 32 m-tiles x 4 n-tiles = 1024 blocks
  moe_gemm2p<FH, DM, false><<<NE * 32 * (DM / 256), 512, 0, stream>>>(
      hbuf, W2T, b2, cnt, base, ent_tok, ent_w, nullptr, ybuf);
  combine_k<<<TTOK * DM / 4 / 256, 256, 0, stream>>>(ybuf, out, TTOK * DM / 4);
}

// Round 9
// 856.309 us; speedup vs baseline: 1.3639x; 1.3639x over previous
//
#include <hip/hip_runtime.h>
#include <hip/hip_bf16.h>
#include <math.h>

#define TTOK 8192
#define DM   1024
#define NE   8
#define FH   4096
#define ECAP 8192

typedef __attribute__((ext_vector_type(8))) short bf16x8;
typedef __attribute__((ext_vector_type(4))) float f32x4;

__device__ __forceinline__ unsigned short f2bf(float f) {
  union { float f; unsigned u; } v; v.f = f;
  unsigned r = v.u + 0x7fffu + ((v.u >> 16) & 1u);
  return (unsigned short)(r >> 16);
}

// async global->LDS, 16B per lane; LDS dst must be wave-uniform-base + lane*16
__device__ __forceinline__ void async16(const unsigned short* g, unsigned short* l) {
  __builtin_amdgcn_global_load_lds(
      (const __attribute__((address_space(1))) void*)g,
      (__attribute__((address_space(3))) void*)l, 16, 0, 0);
}

// exact-gelu via Abramowitz-Stegun 7.1.26 erf approx (|err| <= 1.5e-7)
__device__ __forceinline__ float gelu_erf(float v) {
  float x = v * 0.70710678118654752f;
  float ax = fabsf(x);
  float t = __frcp_rn(1.0f + 0.3275911f * ax);
  float poly = t * (0.254829592f + t * (-0.284496736f +
               t * (1.421413741f + t * (-1.453152027f + t * 1.061405429f))));
  float erfa = 1.0f - poly * __expf(-ax * ax);
  float erfx = copysignf(erfa, x);
  return 0.5f * v * (1.0f + erfx);
}

// ---------------- x -> bf16 ----------------
__global__ void cvt_x(const float* __restrict__ x, unsigned short* __restrict__ xb, int n4) {
  int id = blockIdx.x * 256 + threadIdx.x;
  if (id >= n4) return;
  float4 v = ((const float4*)x)[id];
  ushort4 o;
  o.x = f2bf(v.x); o.y = f2bf(v.y); o.z = f2bf(v.z); o.w = f2bf(v.w);
  ((ushort4*)xb)[id] = o;
}

// ---------------- fp32 [NE][R][Cc] -> bf16 [NE][Cc][R] (transpose+convert) ----
__global__ __launch_bounds__(256) void transpose_cvt(
    const float* __restrict__ src, unsigned short* __restrict__ dst, int R, int Cc) {
  __shared__ unsigned short t[64 * 72];
  int e = blockIdx.z;
  int c0 = blockIdx.x * 64, r0 = blockIdx.y * 64;
  int tid = threadIdx.x;
  const float* sp = src + (size_t)e * R * Cc;
  unsigned short* dp = dst + (size_t)e * R * Cc;
#pragma unroll
  for (int p = 0; p < 4; ++p) {
    int idx = p * 256 + tid;
    int row = idx >> 4;
    int c4 = (idx & 15) * 4;
    float4 v = *(const float4*)(sp + (size_t)(r0 + row) * Cc + c0 + c4);
    t[(c4 + 0) * 72 + row] = f2bf(v.x);
    t[(c4 + 1) * 72 + row] = f2bf(v.y);
    t[(c4 + 2) * 72 + row] = f2bf(v.z);
    t[(c4 + 3) * 72 + row] = f2bf(v.w);
  }
  __syncthreads();
#pragma unroll
  for (int p = 0; p < 4; ++p) {
    int idx = p * 256 + tid;
    int crow = idx >> 4;
    int r4 = (idx & 15) * 4;
    ushort4 o = *(ushort4*)(&t[crow * 72 + r4]);
    *(ushort4*)(dp + (size_t)(c0 + crow) * R + r0 + r4) = o;
  }
}

// ---------------- gating: softmax + top2, per-token store (NO atomics) -------
__global__ __launch_bounds__(256) void gate_kernel(
    const float* __restrict__ x, const float* __restrict__ wg,
    int* __restrict__ tok_e, float* __restrict__ tok_w) {
  __shared__ float wls[NE * DM];
  int tid = threadIdx.x;
  for (int i = tid; i < NE * DM / 4; i += 256)
    ((float4*)wls)[i] = ((const float4*)wg)[i];
  __syncthreads();

  int wave = tid >> 6, lane = tid & 63;
  int t = blockIdx.x * 4 + wave;
  const float* xp = x + (size_t)t * DM;
  float acc[NE];
#pragma unroll
  for (int e = 0; e < NE; ++e) acc[e] = 0.f;
#pragma unroll
  for (int i = 0; i < 16; ++i) {
    float xv = xp[i * 64 + lane];
#pragma unroll
    for (int e = 0; e < NE; ++e) acc[e] += xv * wls[e * DM + i * 64 + lane];
  }
#pragma unroll
  for (int e = 0; e < NE; ++e) {
    float v = acc[e];
    for (int off = 32; off; off >>= 1) v += __shfl_xor(v, off, 64);
    acc[e] = v;
  }
  if (lane == 0) {
    float mx = acc[0];
#pragma unroll
    for (int e = 1; e < NE; ++e) mx = fmaxf(mx, acc[e]);
    float p[NE], s = 0.f;
#pragma unroll
    for (int e = 0; e < NE; ++e) { p[e] = __expf(acc[e] - mx); s += p[e]; }
    float inv = 1.f / s;
#pragma unroll
    for (int e = 0; e < NE; ++e) p[e] *= inv;
    int i0 = 0; float m0v = p[0];
#pragma unroll
    for (int e = 1; e < NE; ++e) if (p[e] > m0v) { m0v = p[e]; i0 = e; }
    int i1 = -1; float m1v = -1.f;
#pragma unroll
    for (int e = 0; e < NE; ++e) if (e != i0 && p[e] > m1v) { m1v = p[e]; i1 = e; }
    tok_e[t] = i0 | (i1 << 8);
    tok_w[2 * t]     = m0v;
    tok_w[2 * t + 1] = m1v;
  }
}

// ---------------- bucket build: 1 block per expert, LDS scan, no atomics -----
__global__ __launch_bounds__(1024) void bucket_kernel(
    const int* __restrict__ tok_e, const float* __restrict__ tok_w,
    int* __restrict__ cnt, int* __restrict__ ent_tok, float* __restrict__ ent_w) {
  const int e = blockIdx.x;          // expert
  const int tid = threadIdx.x;       // 1024 threads x 8 tokens = 8192
  __shared__ int sc[1024];
  int te[8];
  *(int4*)(&te[0]) = *(const int4*)(tok_e + tid * 8);
  *(int4*)(&te[4]) = *(const int4*)(tok_e + tid * 8 + 4);
  int c = 0;
#pragma unroll
  for (int i = 0; i < 8; ++i) {
    c += ((te[i] & 255) == e);
    c += (((te[i] >> 8) & 255) == e);
  }
  sc[tid] = c;
  __syncthreads();
  // Hillis-Steele inclusive scan over 1024 threads
  for (int off = 1; off < 1024; off <<= 1) {
    int v = sc[tid];
    int add = (tid >= off) ? sc[tid - off] : 0;
    __syncthreads();
    sc[tid] = v + add;
    __syncthreads();
  }
  int pos = sc[tid] - c;             // exclusive prefix for this thread
  if (tid == 1023) cnt[e] = sc[1023];
#pragma unroll
  for (int i = 0; i < 8; ++i) {
    int t = tid * 8 + i;
    int e0 = te[i] & 255, e1 = (te[i] >> 8) & 255;
    if (e0 == e) { ent_tok[e * ECAP + pos] = 2 * t;     ent_w[e * ECAP + pos] = tok_w[2 * t];     ++pos; }
    if (e1 == e) { ent_tok[e * ECAP + pos] = 2 * t + 1; ent_w[e * ECAP + pos] = tok_w[2 * t + 1]; ++pos; }
  }
}

// ---------------- exclusive scan of expert counts ----------------
__global__ void scan_cnt(const int* __restrict__ cnt, int* __restrict__ base) {
  if (threadIdx.x == 0) {
    int s = 0;
    for (int e = 0; e < NE; ++e) { base[e] = s; s += cnt[e]; }
  }
}

#define ISSUE_A(buf, k0)                                         \
  async16(asrc0 + (k0), &As[buf][tid * 8]);                      \
  async16(asrc1 + (k0), &As[buf][2048 + tid * 8]);

#define COMPUTE(buf)                                                           \
  {                                                                            \
    bf16x8 af[4], bfr[4];                                                      \
    _Pragma("unroll") for (int im = 0; im < 4; ++im)                           \
      af[im] = *(const bf16x8*)(&As[buf][(wm * 64 + im * 16 + l16) * 32 + q * 8]); \
    _Pragma("unroll") for (int in = 0; in < 4; ++in)                           \
      bfr[in] = *(const bf16x8*)(&Bs[buf][(wn * 64 + in * 16 + l16) * 32 + q * 8]); \
    _Pragma("unroll") for (int im = 0; im < 4; ++im)                           \
      _Pragma("unroll") for (int in = 0; in < 4; ++in)                         \
        acc[im][in] = __builtin_amdgcn_mfma_f32_16x16x32_bf16(af[im], bfr[in], acc[im][in], 0, 0, 0); \
  }

// ---------------- GEMM1: hbuf[be+i] = gelu(gather(xb) @ W1T^T + b1) -----------
// 1D grid 16384: e = bid&7 (XCD-pinned), j=bid>>3, n-outer/m-inner
__global__ __launch_bounds__(256) void moe_gemm1(
    const unsigned short* __restrict__ xb, const unsigned short* __restrict__ W1T,
    const float* __restrict__ b1, const int* __restrict__ cnt,
    const int* __restrict__ base, const int* __restrict__ ent_tok,
    unsigned short* __restrict__ hbuf) {
  const int bid = blockIdx.x;
  const int e = bid & 7;
  const int j = bid >> 3;
  const int n0 = (j >> 6) * 128;
  const int m0 = (j & 63) * 128;
  const int C = cnt[e];
  if (m0 >= C) return;
  const int be = base[e];
  const int tid = threadIdx.x;
  const int lane = tid & 63, wave = tid >> 6;
  const int wm = wave & 1, wn = wave >> 1;
  const int q = lane >> 4, l16 = lane & 15;

  __shared__ unsigned short As[2][128 * 32];
  __shared__ unsigned short Bs[2][128 * 32];
  __shared__ float bls[128];

  if (tid < 128) bls[tid] = b1[e * FH + n0 + tid];

  const int r = tid >> 2;
  const int kq = (tid & 3) * 8;
  int i0 = m0 + r;      if (i0 >= C) i0 = C - 1;
  int i1 = m0 + r + 64; if (i1 >= C) i1 = C - 1;
  const unsigned short* asrc0 = xb + (size_t)(ent_tok[e * ECAP + i0] >> 1) * DM + kq;
  const unsigned short* asrc1 = xb + (size_t)(ent_tok[e * ECAP + i1] >> 1) * DM + kq;
  const unsigned short* bsrc  = W1T + ((size_t)e * FH + n0 + r) * DM + kq;

  f32x4 acc[4][4];
#pragma unroll
  for (int i = 0; i < 4; ++i)
#pragma unroll
    for (int jj = 0; jj < 4; ++jj) acc[i][jj] = (f32x4){0.f, 0.f, 0.f, 0.f};

  // prologue: k=0 into buf 0
  ISSUE_A(0, 0)
  async16(bsrc, &Bs[0][tid * 8]);
  async16(bsrc + (size_t)64 * DM, &Bs[0][2048 + tid * 8]);

#pragma unroll 1
  for (int k0 = 0; k0 < DM; k0 += 64) {
    __syncthreads();               // drains buf0(k0) loads (in flight for a full phase)
    if (k0 + 32 < DM) {
      ISSUE_A(1, k0 + 32)
      async16(bsrc + k0 + 32, &Bs[1][tid * 8]);
      async16(bsrc + (size_t)64 * DM + k0 + 32, &Bs[1][2048 + tid * 8]);
    }
    COMPUTE(0)
    __syncthreads();               // drains buf1(k0+32) loads
    if (k0 + 64 < DM) {
      ISSUE_A(0, k0 + 64)
      async16(bsrc + k0 + 64, &Bs[0][tid * 8]);
      async16(bsrc + (size_t)64 * DM + k0 + 64, &Bs[0][2048 + tid * 8]);
    }
    COMPUTE(1)
  }

#pragma unroll
  for (int im = 0; im < 4; ++im)
#pragma unroll
    for (int rr = 0; rr < 4; ++rr) {
      int gm = m0 + wm * 64 + im * 16 + q * 4 + rr;
      if (gm >= C) continue;
      size_t bas = (size_t)(be + gm) * FH;
#pragma unroll
      for (int in = 0; in < 4; ++in) {
        int n = wn * 64 + in * 16 + l16;
        float v = acc[im][in][rr] + bls[n];
        hbuf[bas + n0 + n] = f2bf(gelu_erf(v));
      }
    }
}

// ---------------- GEMM2: ybuf[rowid] = w * (hbuf[be+m] @ W2T^T + b2) ----------
// 1D grid 4096: e = bid&7 (XCD-pinned), j=bid>>3, n-outer/m-inner
__global__ __launch_bounds__(256) void moe_gemm2(
    const unsigned short* __restrict__ hbuf, const unsigned short* __restrict__ W2T,
    const float* __restrict__ b2, const int* __restrict__ cnt,
    const int* __restrict__ base, const int* __restrict__ ent_tok,
    const float* __restrict__ ent_w, float* __restrict__ ybuf) {
  const int bid = blockIdx.x;
  const int e = bid & 7;
  const int j = bid >> 3;
  const int n0 = (j >> 6) * 128;
  const int m0 = (j & 63) * 128;
  const int C = cnt[e];
  if (m0 >= C) return;
  const int be = base[e];
  const int tid = threadIdx.x;
  const int lane = tid & 63, wave = tid >> 6;
  const int wm = wave & 1, wn = wave >> 1;
  const int q = lane >> 4, l16 = lane & 15;

  __shared__ unsigned short As[2][128 * 32];
  __shared__ unsigned short Bs[2][128 * 32];
  __shared__ float bls[128];

  if (tid < 128) bls[tid] = b2[e * DM + n0 + tid];

  const int r = tid >> 2;
  const int kq = (tid & 3) * 8;
  int i0 = m0 + r;      if (i0 >= C) i0 = C - 1;
  int i1 = m0 + r + 64; if (i1 >= C) i1 = C - 1;
  const unsigned short* asrc0 = hbuf + (size_t)(be + i0) * FH + kq;
  const unsigned short* asrc1 = hbuf + (size_t)(be + i1) * FH + kq;
  const unsigned short* bsrc  = W2T + ((size_t)e * DM + n0 + r) * FH + kq;

  f32x4 acc[4][4];
#pragma unroll
  for (int i = 0; i < 4; ++i)
#pragma unroll
    for (int jj = 0; jj < 4; ++jj) acc[i][jj] = (f32x4){0.f, 0.f, 0.f, 0.f};

  ISSUE_A(0, 0)
  async16(bsrc, &Bs[0][tid * 8]);
  async16(bsrc + (size_t)64 * FH, &Bs[0][2048 + tid * 8]);

#pragma unroll 1
  for (int k0 = 0; k0 < FH; k0 += 64) {
    __syncthreads();
    if (k0 + 32 < FH) {
      ISSUE_A(1, k0 + 32)
      async16(bsrc + k0 + 32, &Bs[1][tid * 8]);
      async16(bsrc + (size_t)64 * FH + k0 + 32, &Bs[1][2048 + tid * 8]);
    }
    COMPUTE(0)
    __syncthreads();
    if (k0 + 64 < FH) {
      ISSUE_A(0, k0 + 64)
      async16(bsrc + k0 + 64, &Bs[0][tid * 8]);
      async16(bsrc + (size_t)64 * FH + k0 + 64, &Bs[0][2048 + tid * 8]);
    }
    COMPUTE(1)
  }

#pragma unroll
  for (int im = 0; im < 4; ++im)
#pragma unroll
    for (int rr = 0; rr < 4; ++rr) {
      int gm = m0 + wm * 64 + im * 16 + q * 4 + rr;
      if (gm >= C) continue;
      int rowid = ent_tok[e * ECAP + gm];
      float w = ent_w[e * ECAP + gm];
      size_t bas = (size_t)rowid * DM;
#pragma unroll
      for (int in = 0; in < 4; ++in) {
        int n = wn * 64 + in * 16 + l16;
        ybuf[bas + n0 + n] = w * (acc[im][in][rr] + bls[n]);
      }
    }
}

// ---------------- combine: out[t] = y[2t] + y[2t+1] ----------------
__global__ void combine_k(const float* __restrict__ y, float* __restrict__ out, int n4) {
  int id = blockIdx.x * 256 + threadIdx.x;
  if (id >= n4) return;
  int t = id >> 8;   // 256 float4 per 1024-elem row
  int c = id & 255;
  float4 a = ((const float4*)y)[((size_t)t * 2) * 256 + c];
  float4 b = ((const float4*)y)[((size_t)t * 2 + 1) * 256 + c];
  float4 o = {a.x + b.x, a.y + b.y, a.z + b.z, a.w + b.w};
  ((float4*)out)[id] = o;
}

extern "C" void kernel_launch(void* const* d_in, const int* in_sizes, int n_in,
                              void* d_out, int out_size, void* d_ws, size_t ws_size,
                              hipStream_t stream) {
  const float* x  = (const float*)d_in[0];
  const float* wg = (const float*)d_in[1];
  const float* W1 = (const float*)d_in[2];
  const float* b1 = (const float*)d_in[3];
  const float* W2 = (const float*)d_in[4];
  const float* b2 = (const float*)d_in[5];
  float* out = (float*)d_out;

  char* ws = (char*)d_ws;
  size_t off = 0;
  unsigned short* xb = (unsigned short*)(ws + off); off += (size_t)TTOK * DM * 2;        // 16 MB
  int* cnt = (int*)(ws + off); off += 128;
  int* base = (int*)(ws + off); off += 128;
  int* ent_tok = (int*)(ws + off); off += (size_t)NE * ECAP * 4;                         // 256 KB
  float* ent_w = (float*)(ws + off); off += (size_t)NE * ECAP * 4;                       // 256 KB
  int* tok_e = (int*)(ws + off); off += (size_t)TTOK * 4;                                // 32 KB
  float* tok_w = (float*)(ws + off); off += (size_t)TTOK * 2 * 4;                        // 64 KB
  unsigned short* W1T = (unsigned short*)(ws + off); off += (size_t)NE * DM * FH * 2;    // 64 MB
  unsigned short* W2T = (unsigned short*)(ws + off); off += (size_t)NE * FH * DM * 2;    // 64 MB
  unsigned short* hbuf = (unsigned short*)(ws + off); off += (size_t)TTOK * 2 * FH * 2;  // 128 MB
  // ybuf overlays W1T: W1T is dead after gemm1, regenerated next launch before gemm1
  float* ybuf = (float*)W1T;                                                             // 64 MB

  cvt_x<<<TTOK * DM / 4 / 256, 256, 0, stream>>>(x, xb, TTOK * DM / 4);
  gate_kernel<<<TTOK / 4, 256, 0, stream>>>(x, wg, tok_e, tok_w);
  bucket_kernel<<<NE, 1024, 0, stream>>>(tok_e, tok_w, cnt, ent_tok, ent_w);
  scan_cnt<<<1, 64, 0, stream>>>(cnt, base);
  dim3 t1(FH / 64, DM / 64, NE);
  transpose_cvt<<<t1, 256, 0, stream>>>(W1, W1T, DM, FH);
  dim3 t2(DM / 64, FH / 64, NE);
  transpose_cvt<<<t2, 256, 0, stream>>>(W2, W2T, FH, DM);
  moe_gemm1<<<16384, 256, 0, stream>>>(xb, W1T, b1, cnt, base, ent_tok, hbuf);
  moe_gemm2<<<4096, 256, 0, stream>>>(hbuf, W2T, b2, cnt, base, ent_tok, ent_w, ybuf);
  combine_k<<<TTOK * DM / 4 / 256, 256, 0, stream>>>(ybuf, out, TTOK * DM / 4);
}